// Round 14
// baseline (1402.340 us; speedup 1.0000x reference)
//
#include <hip/hip_runtime.h>
#include <hip/hip_bf16.h>

#define B_ 4
#define L_ 201
#define C_ 55
#define D_ 512
#define F_ 2048
#define N_ 200
#define KT_ 20
#define KC_ 10
#define ROWS_ 44220          // B*L*C
#define CD_ (C_*D_)
#define MPAD_ 44416          // 347*128, padded M for MFMA A-tiles
#define MTC_ 4620            // 220*21 compact temporal rows
#define MTCP_ 4736           // 37*128
#define MCC_ 8040            // 804*10 compact channel rows
#define MCCP_ 8064           // 63*128

using hbf = __hip_bfloat16;
typedef float f32x4 __attribute__((ext_vector_type(4)));
typedef short s16x8 __attribute__((ext_vector_type(8)));

static __device__ __forceinline__ float bf2f(hbf v){ return __bfloat162float(v); }
static __device__ __forceinline__ void cvtS(float* p, float v){ *p = v; }
static __device__ __forceinline__ void cvtS(hbf* p, float v){ *p = __float2bfloat16(v); }

#define GL2LDS16(g, l) __builtin_amdgcn_global_load_lds( \
    (const __attribute__((address_space(1))) void*)(g),  \
    (__attribute__((address_space(3))) void*)(l), 16, 0, 0)

static __device__ __forceinline__ float waveAllSum(float v){
  #pragma unroll
  for (int off = 32; off; off >>= 1) v += __shfl_xor(v, off);
  return v;
}

// ---------------- Threefry-2x32 (exact JAX semantics) ----------------
static __device__ __forceinline__ void tf2x32(unsigned k0, unsigned k1, unsigned x0, unsigned x1,
                                              unsigned &o0, unsigned &o1)
{
  const unsigned k2 = k0 ^ k1 ^ 0x1BD11BDAu;
  unsigned v0 = x0 + k0, v1 = x1 + k1;
  #define TFR(r) { v0 += v1; v1 = (v1 << (r)) | (v1 >> (32 - (r))); v1 ^= v0; }
  TFR(13) TFR(15) TFR(26) TFR(6)
  v0 += k1; v1 += k2 + 1u;
  TFR(17) TFR(29) TFR(16) TFR(24)
  v0 += k2; v1 += k0 + 2u;
  TFR(13) TFR(15) TFR(26) TFR(6)
  v0 += k0; v1 += k1 + 3u;
  TFR(17) TFR(29) TFR(16) TFR(24)
  v0 += k1; v1 += k2 + 4u;
  TFR(13) TFR(15) TFR(26) TFR(6)
  v0 += k2; v1 += k0 + 5u;
  #undef TFR
  o0 = v0; o1 = v1;
}
static __device__ __forceinline__ float tfu(unsigned bits){
  return __uint_as_float((bits >> 9) | 0x3f800000u) - 1.0f;
}
static __device__ __forceinline__ unsigned tf_flat(unsigned k0, unsigned k1, int m, int H){
  unsigned o0, o1;
  if (m < H) { tf2x32(k0, k1, (unsigned)m, (unsigned)(H + m), o0, o1); return o0; }
  tf2x32(k0, k1, (unsigned)(m - H), (unsigned)m, o0, o1); return o1;
}

__global__ void pert_kernel(float* __restrict__ pertT, float* __restrict__ pertC)
{
  int t = blockIdx.x * blockDim.x + threadIdx.x;
  if (t < 55 * 800) {
    int c = t / 800, j = t % 800;
    unsigned kc0 = tf_flat(0u, 42u, 2 * c, 55);
    unsigned kc1 = tf_flat(0u, 42u, 2 * c + 1, 55);
    unsigned bits = tf_flat(kc0, kc1, j, 400);
    pertT[t] = tfu(bits) * 1e-6f;
  } else if (t < 55 * 800 + 220) {
    int j = t - 55 * 800;
    unsigned bits = tf_flat(0u, 7u, j, 110);
    pertC[j] = tfu(bits) * 1e-6f;
  }
}

// ---------------- clustering ----------------
static __device__ __forceinline__ size_t pt_base(int mode, int p, int i){
  if (mode == 0) { int c = p / B_, b = p % B_; return ((size_t)(b * L_ + 1 + i) * C_ + c) * D_; }
  return ((size_t)(p * L_) * C_ + i) * D_;
}

__global__ __launch_bounds__(256) void x2_kernel(const float* __restrict__ x, float* __restrict__ x2,
                                                 int nrows, int npts, int mode)
{
  int row = blockIdx.x * 4 + (threadIdx.x >> 6);
  int lane = threadIdx.x & 63;
  if (row >= nrows) return;
  int p = row / npts, i = row % npts;
  const float* px = x + pt_base(mode, p, i);
  float s = 0.f;
  #pragma unroll
  for (int u = 0; u < 8; ++u) { float v = px[lane + u * 64]; s = fmaf(v, v, s); }
  s = waveAllSum(s);
  if (lane == 0) x2[row] = s;
}

// symmetric-pair 64x64-tile distance kernel, BK=32; mirror via LDS transpose OVERLAID on As/Bs
__global__ __launch_bounds__(256) void dist64_kernel(const float* __restrict__ x, const float* __restrict__ x2,
    float* __restrict__ dist, unsigned* __restrict__ dmax, int npts, int nt, int mode)
{
  const int p = blockIdx.y;
  int idx = blockIdx.x;
  int ti = 0;
  while (idx >= nt - ti) { idx -= nt - ti; ++ti; }
  const int tj = ti + idx;
  const int i0 = ti * 64, j0 = tj * 64;
  const int tid = threadIdx.x;
  const int tx = tid & 15, ty = tid >> 4;
  const int ar = tid >> 2, ak = (tid & 3) * 8;
  __shared__ __align__(16) char dsm[17408];     // As[32][68] | Bs[32][68]  -> reused as Ts[64][65]
  float (*As)[68] = (float(*)[68])dsm;
  float (*Bs)[68] = (float(*)[68])(dsm + 8704);
  float (*Ts)[65] = (float(*)[65])dsm;
  __shared__ unsigned bmax;
  if (tid == 0) bmax = 0u;
  int ia = i0 + ar; if (ia >= npts) ia = npts - 1;
  int jb = j0 + ar; if (jb >= npts) jb = npts - 1;
  const size_t baseA = pt_base(mode, p, ia);
  const size_t baseB = pt_base(mode, p, jb);
  float acc[4][4] = {};
  for (int k0 = 0; k0 < D_; k0 += 32) {
    float4 la0 = *(const float4*)&x[baseA + k0 + ak];
    float4 la1 = *(const float4*)&x[baseA + k0 + ak + 4];
    float4 lb0 = *(const float4*)&x[baseB + k0 + ak];
    float4 lb1 = *(const float4*)&x[baseB + k0 + ak + 4];
    __syncthreads();
    As[ak + 0][ar] = la0.x; As[ak + 1][ar] = la0.y; As[ak + 2][ar] = la0.z; As[ak + 3][ar] = la0.w;
    As[ak + 4][ar] = la1.x; As[ak + 5][ar] = la1.y; As[ak + 6][ar] = la1.z; As[ak + 7][ar] = la1.w;
    Bs[ak + 0][ar] = lb0.x; Bs[ak + 1][ar] = lb0.y; Bs[ak + 2][ar] = lb0.z; Bs[ak + 3][ar] = lb0.w;
    Bs[ak + 4][ar] = lb1.x; Bs[ak + 5][ar] = lb1.y; Bs[ak + 6][ar] = lb1.z; Bs[ak + 7][ar] = lb1.w;
    __syncthreads();
    #pragma unroll
    for (int kk = 0; kk < 32; ++kk) {
      float4 av = *(const float4*)&As[kk][ty * 4];
      float4 bv = *(const float4*)&Bs[kk][tx * 4];
      float a4[4] = {av.x, av.y, av.z, av.w};
      float b4[4] = {bv.x, bv.y, bv.z, bv.w};
      #pragma unroll
      for (int u = 0; u < 4; ++u)
        #pragma unroll
        for (int v = 0; v < 4; ++v) acc[u][v] = fmaf(a4[u], b4[v], acc[u][v]);
    }
  }
  __syncthreads();
  unsigned lmax = 0u;
  #pragma unroll
  for (int u = 0; u < 4; ++u) {
    int i = i0 + ty * 4 + u;
    #pragma unroll
    for (int v = 0; v < 4; ++v) {
      int j = j0 + tx * 4 + v;
      if (i < npts && j < npts) {
        float d2 = x2[p * npts + i] + x2[p * npts + j] - 2.0f * acc[u][v];
        float dv = sqrtf(fmaxf(d2, 0.0f)) / 22.627416997969522f;
        dist[((size_t)p * npts + i) * npts + j] = dv;
        Ts[tx * 4 + v][ty * 4 + u] = dv;
        unsigned b = __float_as_uint(dv);
        if (b > lmax) lmax = b;
      }
    }
  }
  atomicMax(&bmax, lmax);
  __syncthreads();
  if (ti != tj) {
    const int jj = tid >> 2, iiB = (tid & 3) * 16;
    int gj = j0 + jj;
    if (gj < npts) {
      float* drow = dist + ((size_t)p * npts + gj) * npts + i0;
      #pragma unroll
      for (int v = 0; v < 16; ++v) {
        int ii = iiB + v;
        if (i0 + ii < npts) drow[ii] = Ts[jj][ii];
      }
    }
  }
  if (tid == 0) atomicMax(&dmax[p], bmax);
}

__global__ __launch_bounds__(256) void knn_density_kernel(const float* __restrict__ dist,
    const float* __restrict__ pert, float* __restrict__ density, int nrows, int npts, int kk, int mode)
{
  int row = blockIdx.x * 4 + (threadIdx.x >> 6);
  int lane = threadIdx.x & 63;
  if (row >= nrows) return;
  const float INF = __int_as_float(0x7f800000);
  const float* dr = dist + (size_t)row * npts;
  float vals[4];
  #pragma unroll
  for (int u = 0; u < 4; ++u) { int j = lane + u * 64; vals[u] = (j < npts) ? dr[j] : INF; }
  float acc = 0.f;
  for (int it = 0; it < kk; ++it) {
    float m = fminf(fminf(vals[0], vals[1]), fminf(vals[2], vals[3]));
    #pragma unroll
    for (int off = 32; off; off >>= 1) m = fminf(m, __shfl_xor(m, off));
    acc += m * m;
    bool has = (vals[0] == m) || (vals[1] == m) || (vals[2] == m) || (vals[3] == m);
    unsigned long long bal = __ballot(has);
    int fl = __ffsll(bal) - 1;
    if (lane == fl) {
      if (vals[0] == m) vals[0] = INF;
      else if (vals[1] == m) vals[1] = INF;
      else if (vals[2] == m) vals[2] = INF;
      else vals[3] = INF;
    }
  }
  if (lane == 0) {
    float mean = acc / (float)kk;
    int pidx;
    if (mode == 0) { int p = row / npts; int i = row - p * npts; int c = p / B_, b = p % B_; pidx = c * 800 + b * 200 + i; }
    else pidx = row;
    density[row] = expf(-mean) + pert[pidx];
  }
}

// wave-per-row d_parent + score
__global__ __launch_bounds__(256) void dparent_score_kernel(const float* __restrict__ dist,
    const float* __restrict__ density, const unsigned* __restrict__ dmax, float* __restrict__ score,
    int nrows, int npts)
{
  int row = blockIdx.x * 4 + (threadIdx.x >> 6);
  int lane = threadIdx.x & 63;
  if (row >= nrows) return;
  int p = row / npts;
  float di = density[row];
  const float* dr = dist + (size_t)row * npts;
  const float* de = density + (size_t)p * npts;
  float mn = __int_as_float(0x7f800000);
  #pragma unroll
  for (int u = 0; u < 4; ++u) {
    int j = lane + u * 64;
    if (j < npts && de[j] > di) mn = fminf(mn, dr[j]);
  }
  #pragma unroll
  for (int off = 32; off; off >>= 1) mn = fminf(mn, __shfl_xor(mn, off));
  if (lane == 0) {
    float dp = fminf(mn, __uint_as_float(dmax[p]));
    score[row] = dp * di;
  }
}

// seeds + assignment; also emits raw cluster counts
__global__ __launch_bounds__(256) void seeds_assign_kernel(const float* __restrict__ score,
    const float* __restrict__ dist, int* __restrict__ idx, float* __restrict__ nw,
    int* __restrict__ cntOut, int npts, int K)
{
  const int p = blockIdx.x;
  const int t = threadIdx.x;
  __shared__ float s[N_];
  __shared__ int seeds[KT_];
  __shared__ int lidx[N_];
  __shared__ int cnt[KT_];
  for (int e = t; e < npts; e += 256) s[e] = score[(size_t)p * npts + e];
  if (t < K) cnt[t] = 0;
  __syncthreads();
  if (t == 0) {
    for (int k2 = 0; k2 < K; ++k2) {
      float best = -1.f; int bi = 0;
      for (int n = 0; n < npts; ++n) if (s[n] > best) { best = s[n]; bi = n; }
      seeds[k2] = bi; s[bi] = -2.f;
    }
  }
  __syncthreads();
  for (int e = t; e < npts; e += 256) {
    float best = __int_as_float(0x7f800000); int bk = 0;
    for (int k2 = 0; k2 < K; ++k2) {
      float dv = dist[((size_t)p * npts + seeds[k2]) * npts + e];
      if (dv < best) { best = dv; bk = k2; }
    }
    lidx[e] = bk;
  }
  __syncthreads();
  if (t < K) lidx[seeds[t]] = t;
  __syncthreads();
  for (int e = t; e < npts; e += 256) atomicAdd(&cnt[lidx[e]], 1);
  __syncthreads();
  for (int e = t; e < npts; e += 256) idx[(size_t)p * npts + e] = lidx[e];
  if (t < K) {
    nw[p * K + t] = 1.0f / ((float)cnt[t] + 1e-6f);
    cntOut[p * K + t] = cnt[t];
  }
}

__global__ __launch_bounds__(128) void merge_t_kernel(const float* __restrict__ x, const int* __restrict__ idx,
    const float* __restrict__ nw, float* __restrict__ merged)
{
  const int dc = blockIdx.x;
  const int p  = blockIdx.y;
  const int c = p / B_, b = p % B_;
  const int t = threadIdx.x;
  __shared__ float acc[KT_][128];
  __shared__ int li[N_];
  __shared__ float lw[KT_];
  for (int e = t; e < N_; e += 128) li[e] = idx[p * N_ + e];
  if (t < KT_) lw[t] = nw[p * KT_ + t];
  #pragma unroll
  for (int k2 = 0; k2 < KT_; ++k2) acc[k2][t] = 0.f;
  __syncthreads();
  const float* px = x + ((size_t)(b * L_ + 1) * C_ + c) * D_ + dc * 128 + t;
  for (int n = 0; n < N_; ++n) {
    int kt = li[n];
    acc[kt][t] += px[(size_t)n * CD_] * lw[kt];
  }
  __syncthreads();
  for (int k2 = 0; k2 < KT_; ++k2)
    merged[((size_t)p * KT_ + k2) * D_ + dc * 128 + t] = acc[k2][t];
}

__global__ __launch_bounds__(128) void merge_c_kernel(const float* __restrict__ x, const int* __restrict__ idxc,
    const float* __restrict__ nwc, float* __restrict__ merged)
{
  const int bl = blockIdx.x;
  const int dc = blockIdx.y;
  const int b = bl / L_, l = bl % L_;
  const int t = threadIdx.x;
  __shared__ float acc[KC_][128];
  __shared__ int li[C_];
  __shared__ float lw[KC_];
  if (t < C_) li[t] = idxc[b * C_ + t];
  if (t < KC_) lw[t] = nwc[b * KC_ + t];
  #pragma unroll
  for (int k2 = 0; k2 < KC_; ++k2) acc[k2][t] = 0.f;
  __syncthreads();
  const float* px = x + ((size_t)(b * L_ + l) * C_) * D_ + dc * 128 + t;
  for (int cc = 0; cc < C_; ++cc) {
    int kc = li[cc];
    acc[kc][t] += px[(size_t)cc * D_] * lw[kc];
  }
  __syncthreads();
  for (int k2 = 0; k2 < KC_; ++k2)
    merged[((size_t)(b * L_ + l) * KC_ + k2) * D_ + dc * 128 + t] = acc[k2][t];
}

// ---------------- compact A-matrix builders ----------------
__global__ void build_xac_bf(const float* __restrict__ ori, const float* __restrict__ merged,
                             hbf* __restrict__ xa)
{
  int e = blockIdx.x * 256 + threadIdx.x;
  if (e >= MTCP_ * 64) return;
  int r = e >> 6, q8 = e & 63;
  hbf tmp[8];
  if (r < MTC_) {
    int p = r / 21, ks = r % 21;
    const float* sp;
    if (ks == 0) {
      int c = p / B_, b = p % B_;
      sp = ori + ((size_t)(b * L_) * C_ + c) * D_ + q8 * 8;
    } else {
      sp = merged + ((size_t)p * KT_ + ks - 1) * D_ + q8 * 8;
    }
    #pragma unroll
    for (int u = 0; u < 8; ++u) tmp[u] = __float2bfloat16(sp[u]);
  } else {
    #pragma unroll
    for (int u = 0; u < 8; ++u) tmp[u] = __float2bfloat16(0.f);
  }
  *(uint4*)(xa + (size_t)r * D_ + q8 * 8) = *(uint4*)tmp;
}

__global__ void cast_xcc_bf(const float* __restrict__ merged, hbf* __restrict__ xc)
{
  int e = blockIdx.x * 256 + threadIdx.x;
  if (e >= MCCP_ * 64) return;
  int r = e >> 6, q8 = e & 63;
  hbf tmp[8];
  if (r < MCC_) {
    const float* sp = merged + (size_t)r * D_ + q8 * 8;
    #pragma unroll
    for (int u = 0; u < 8; ++u) tmp[u] = __float2bfloat16(sp[u]);
  } else {
    #pragma unroll
    for (int u = 0; u < 8; ++u) tmp[u] = __float2bfloat16(0.f);
  }
  *(uint4*)(xc + (size_t)r * D_ + q8 * 8) = *(uint4*)tmp;
}

// ---------------- weight transpose+cast ----------------
__global__ __launch_bounds__(256) void transp_kernel(const float* __restrict__ src, hbf* __restrict__ dst,
                                                     int K, int N)
{
  __shared__ float tile[32][33];
  const int t = threadIdx.x;
  const int tx = t & 31, ry = t >> 5;
  const int n0 = blockIdx.x * 32, k0 = blockIdx.y * 32;
  #pragma unroll
  for (int r = 0; r < 4; ++r)
    tile[ry + r * 8][tx] = src[(size_t)(k0 + ry + r * 8) * N + n0 + tx];
  __syncthreads();
  #pragma unroll
  for (int r = 0; r < 4; ++r)
    dst[(size_t)(n0 + ry + r * 8) * K + k0 + tx] = __float2bfloat16(tile[tx][ry + r * 8]);
}

// ---------------- MFMA GEMM 128x128 (narrow) ----------------
// EPI: 0=store, 1=+bias, 2=+bias+GELU, 4=splitN/512 planes with stride pstride
template<typename TC, int EPI>
__global__ __launch_bounds__(256) void gemm_mfma(const hbf* __restrict__ A, const hbf* __restrict__ BT,
    TC* __restrict__ Cp, const float* __restrict__ bias, int M, int N, int K, size_t pstride)
{
  __shared__ hbf As[128 * 64];
  __shared__ hbf Bs[128 * 64];
  const int tid = threadIdx.x;
  const int nwg = gridDim.x * gridDim.y;
  const int bid = blockIdx.y * gridDim.x + blockIdx.x;
  const int q = nwg >> 3, rr = nwg & 7;
  const int xcd = bid & 7, loc = bid >> 3;
  const int swzid = (xcd < rr) ? (xcd * (q + 1) + loc) : (rr * (q + 1) + (xcd - rr) * q + loc);
  const int row0 = (swzid / gridDim.x) * 128, col0 = (swzid % gridDim.x) * 128;
  const int lane = tid & 63, wid = tid >> 6;
  const int wm = wid & 1, wn = wid >> 1;
  const int lr = lane & 15, lk8 = (lane >> 4) * 8;
  const int srow = wid * 32 + (lane >> 3);
  const int scol = ((lane & 7) ^ (lane >> 3)) * 8;
  const hbf* agp = A + (size_t)(row0 + srow) * K + scol;
  const hbf* bgp = BT + (size_t)(col0 + srow) * K + scol;
  hbf* asw = As + wid * 32 * 64;
  hbf* bsw = Bs + wid * 32 * 64;
  const int swz = (lr & 7) * 8;
  f32x4 acc[4][4] = {};
  for (int k0 = 0; k0 < K; k0 += 64) {
    __syncthreads();
    #pragma unroll
    for (int t = 0; t < 4; ++t) {
      GL2LDS16(agp + k0 + (size_t)t * 8 * K, asw + t * 8 * 64);
      GL2LDS16(bgp + k0 + (size_t)t * 8 * K, bsw + t * 8 * 64);
    }
    asm volatile("s_waitcnt vmcnt(0)" ::: "memory");
    __syncthreads();
    #pragma unroll
    for (int ks = 0; ks < 64; ks += 32) {
      s16x8 af[4], bfr[4];
      #pragma unroll
      for (int i = 0; i < 4; ++i)
        af[i] = *(const s16x8*)&As[(wm * 64 + i * 16 + lr) * 64 + ((ks + lk8) ^ swz)];
      #pragma unroll
      for (int j = 0; j < 4; ++j)
        bfr[j] = *(const s16x8*)&Bs[(wn * 64 + j * 16 + lr) * 64 + ((ks + lk8) ^ swz)];
      #pragma unroll
      for (int i = 0; i < 4; ++i)
        #pragma unroll
        for (int j = 0; j < 4; ++j)
          acc[i][j] = __builtin_amdgcn_mfma_f32_16x16x32_bf16(af[i], bfr[j], acc[i][j], 0, 0, 0);
    }
  }
  #pragma unroll
  for (int i = 0; i < 4; ++i) {
    #pragma unroll
    for (int r = 0; r < 4; ++r) {
      int row = row0 + wm * 64 + i * 16 + (lane >> 4) * 4 + r;
      if (row < M) {
        #pragma unroll
        for (int j = 0; j < 4; ++j) {
          int col = col0 + wn * 64 + j * 16 + lr;
          float val = acc[i][j][r];
          if (EPI == 1 || EPI == 2) val += bias[col];
          if (EPI == 2) val = 0.5f * val * (1.f + erff(val * 0.70710678118654752f));
          if (EPI == 4) {
            cvtS(&Cp[(size_t)(col >> 9) * pstride + (size_t)row * 512 + (col & 511)], val);
          } else {
            cvtS(&Cp[(size_t)row * N + col], val);
          }
        }
      }
    }
  }
}

// ---------------- MFMA GEMM 128x256 (wide, MLP) ----------------
// Same 2-barrier sync structure; per-wave tile 64x128 (acc 4x8). Bit-identical accumulation order.
// EPI: 1=+bias, 2=+bias+GELU
template<typename TC, int EPI>
__global__ __launch_bounds__(256) void gemm_mfma_w(const hbf* __restrict__ A, const hbf* __restrict__ BT,
    TC* __restrict__ Cp, const float* __restrict__ bias, int M, int N, int K)
{
  __shared__ hbf As[128 * 64];
  __shared__ hbf Bs[256 * 64];
  const int tid = threadIdx.x;
  const int nwg = gridDim.x * gridDim.y;
  const int bid = blockIdx.y * gridDim.x + blockIdx.x;
  const int q = nwg >> 3, rr = nwg & 7;
  const int xcd = bid & 7, loc = bid >> 3;
  const int swzid = (xcd < rr) ? (xcd * (q + 1) + loc) : (rr * (q + 1) + (xcd - rr) * q + loc);
  const int row0 = (swzid / gridDim.x) * 128, col0 = (swzid % gridDim.x) * 256;
  const int lane = tid & 63, wid = tid >> 6;
  const int wm = wid & 1, wn = wid >> 1;          // wn in {0,1}: wave cols 128
  const int lr = lane & 15, lk8 = (lane >> 4) * 8;
  const int srowA = wid * 32 + (lane >> 3);
  const int srowB = wid * 64 + (lane >> 3);
  const int scol = ((lane & 7) ^ (lane >> 3)) * 8;
  const hbf* agp = A + (size_t)(row0 + srowA) * K + scol;
  const hbf* bgp = BT + (size_t)(col0 + srowB) * K + scol;
  hbf* asw = As + wid * 32 * 64;
  hbf* bsw = Bs + wid * 64 * 64;
  const int swz = (lr & 7) * 8;
  f32x4 acc[4][8] = {};
  for (int k0 = 0; k0 < K; k0 += 64) {
    __syncthreads();
    #pragma unroll
    for (int t = 0; t < 4; ++t)
      GL2LDS16(agp + k0 + (size_t)t * 8 * K, asw + t * 8 * 64);
    #pragma unroll
    for (int t = 0; t < 8; ++t)
      GL2LDS16(bgp + k0 + (size_t)t * 8 * K, bsw + t * 8 * 64);
    asm volatile("s_waitcnt vmcnt(0)" ::: "memory");
    __syncthreads();
    #pragma unroll
    for (int ks = 0; ks < 64; ks += 32) {
      s16x8 af[4], bfr[8];
      #pragma unroll
      for (int i = 0; i < 4; ++i)
        af[i] = *(const s16x8*)&As[(wm * 64 + i * 16 + lr) * 64 + ((ks + lk8) ^ swz)];
      #pragma unroll
      for (int j = 0; j < 8; ++j)
        bfr[j] = *(const s16x8*)&Bs[(wn * 128 + j * 16 + lr) * 64 + ((ks + lk8) ^ swz)];
      #pragma unroll
      for (int i = 0; i < 4; ++i)
        #pragma unroll
        for (int j = 0; j < 8; ++j)
          acc[i][j] = __builtin_amdgcn_mfma_f32_16x16x32_bf16(af[i], bfr[j], acc[i][j], 0, 0, 0);
    }
  }
  #pragma unroll
  for (int i = 0; i < 4; ++i) {
    #pragma unroll
    for (int r = 0; r < 4; ++r) {
      int row = row0 + wm * 64 + i * 16 + (lane >> 4) * 4 + r;
      if (row < M) {
        #pragma unroll
        for (int j = 0; j < 8; ++j) {
          int col = col0 + wn * 128 + j * 16 + lr;
          float val = acc[i][j][r] + bias[col];
          if (EPI == 2) val = 0.5f * val * (1.f + erff(val * 0.70710678118654752f));
          cvtS(&Cp[(size_t)row * N + col], val);
        }
      }
    }
  }
}

// ---------------- compact temporal attention ----------------
__global__ __launch_bounds__(256) void attn_compact_t(const hbf* __restrict__ Qc, const hbf* __restrict__ Kc,
    const hbf* __restrict__ Vc, const int* __restrict__ cntT, float* __restrict__ PcG, hbf* __restrict__ Oc)
{
  const int p = blockIdx.x;
  const int t = threadIdx.x;
  __shared__ hbf Qs[21 * 512];
  __shared__ hbf Ks[21 * 512];
  __shared__ float Ss[21][22];
  __shared__ float Pw[21][22];
  __shared__ float cnt[21];
  for (int e = t; e < 21 * 64; e += 256) {
    ((uint4*)Qs)[e] = ((const uint4*)(Qc + (size_t)p * 21 * 512))[e];
    ((uint4*)Ks)[e] = ((const uint4*)(Kc + (size_t)p * 21 * 512))[e];
  }
  if (t < 21) cnt[t] = (t == 0) ? 1.0f : (float)cntT[p * KT_ + t - 1];
  __syncthreads();
  for (int pr = t; pr < 441; pr += 256) {
    int qq = pr / 21, kk = pr % 21;
    float s = 0.f;
    #pragma unroll 8
    for (int ch = 0; ch < 64; ++ch) {
      union { s16x8 v; hbf e[8]; } qa, kb;
      qa.v = ((const s16x8*)Qs)[qq * 64 + ch];
      kb.v = ((const s16x8*)Ks)[kk * 64 + ch];
      #pragma unroll
      for (int u = 0; u < 8; ++u)
        s = fmaf(bf2f(qa.e[u]), bf2f(kb.e[u]), s);
    }
    Ss[qq][kk] = s * 0.04419417382415922f;
  }
  __syncthreads();
  if (t < 21) {
    float mx = -3.4e38f;
    for (int kk = 0; kk < 21; ++kk) mx = fmaxf(mx, Ss[t][kk]);
    float den = 0.f;
    for (int kk = 0; kk < 21; ++kk) den += cnt[kk] * expf(Ss[t][kk] - mx);
    float inv = 1.0f / den;
    for (int kk = 0; kk < 21; ++kk) {
      float pc = expf(Ss[t][kk] - mx) * inv;
      Ss[t][kk] = pc;
      Pw[t][kk] = cnt[kk] * pc;
    }
  }
  __syncthreads();
  for (int e = t; e < 441; e += 256) PcG[(size_t)p * 441 + e] = Ss[e / 21][e % 21];
  for (int o = t; o < 21 * 512; o += 256) {
    int qq = o >> 9, d = o & 511;
    float s = 0.f;
    #pragma unroll
    for (int ks = 0; ks < 21; ++ks)
      s = fmaf(Pw[qq][ks], bf2f(Vc[((size_t)p * 21 + ks) * 512 + d]), s);
    Oc[((size_t)p * 21 + qq) * 512 + d] = __float2bfloat16(s);
  }
}

// ---------------- compact channel attention ----------------
__global__ __launch_bounds__(256) void attn_compact_c(const hbf* __restrict__ Qc, const hbf* __restrict__ Kc,
    const hbf* __restrict__ Vc, const int* __restrict__ cntC, hbf* __restrict__ Oc)
{
  const int bl = blockIdx.x;
  const int b = bl / L_;
  const int t = threadIdx.x;
  __shared__ hbf Qs[10 * 512];
  __shared__ hbf Ks[10 * 512];
  __shared__ float Ss[10][12];
  __shared__ float Pw[10][12];
  __shared__ float cnt[10];
  for (int e = t; e < 10 * 64; e += 256) {
    ((uint4*)Qs)[e] = ((const uint4*)(Qc + (size_t)bl * 10 * 512))[e];
    ((uint4*)Ks)[e] = ((const uint4*)(Kc + (size_t)bl * 10 * 512))[e];
  }
  if (t < 10) cnt[t] = (float)cntC[b * KC_ + t];
  __syncthreads();
  if (t < 100) {
    int qq = t / 10, kk = t % 10;
    float s = 0.f;
    #pragma unroll 8
    for (int ch = 0; ch < 64; ++ch) {
      union { s16x8 v; hbf e[8]; } qa, kb;
      qa.v = ((const s16x8*)Qs)[qq * 64 + ch];
      kb.v = ((const s16x8*)Ks)[kk * 64 + ch];
      #pragma unroll
      for (int u = 0; u < 8; ++u)
        s = fmaf(bf2f(qa.e[u]), bf2f(kb.e[u]), s);
    }
    Ss[qq][kk] = s * 0.04419417382415922f;
  }
  __syncthreads();
  if (t < 10) {
    float mx = -3.4e38f;
    for (int kk = 0; kk < 10; ++kk) mx = fmaxf(mx, Ss[t][kk]);
    float den = 0.f;
    for (int kk = 0; kk < 10; ++kk) den += cnt[kk] * expf(Ss[t][kk] - mx);
    float inv = 1.0f / den;
    for (int kk = 0; kk < 10; ++kk) Pw[t][kk] = cnt[kk] * expf(Ss[t][kk] - mx) * inv;
  }
  __syncthreads();
  for (int o = t; o < 10 * 512; o += 256) {
    int qq = o >> 9, d = o & 511;
    float s = 0.f;
    #pragma unroll
    for (int ks = 0; ks < 10; ++ks)
      s = fmaf(Pw[qq][ks], bf2f(Vc[((size_t)bl * 10 + ks) * 512 + d]), s);
    Oc[((size_t)bl * 10 + qq) * 512 + d] = __float2bfloat16(s);
  }
}

// ---------------- expand attn output ----------------
__global__ __launch_bounds__(256) void expand_attn(const float* __restrict__ PcG,
    const int* __restrict__ idxT, float* __restrict__ outA)
{
  const int r = blockIdx.x * 4 + (threadIdx.x >> 6);   // 220*201 rows in (b,c,l)
  const int lane = threadIdx.x & 63;
  const int b = r / (C_ * L_);
  const int rem = r % (C_ * L_);
  const int c = rem / L_, l = rem % L_;
  const int p = c * B_ + b;
  const int qm = (l == 0) ? 0 : idxT[p * N_ + l - 1] + 1;
  const float* Prow = PcG + ((size_t)p * 21 + qm) * 21;
  const int* im = idxT + (size_t)p * N_;
  float* orow = outA + (size_t)r * L_;
  for (int j = lane; j < L_; j += 64) {
    int km = (j == 0) ? 0 : im[j - 1] + 1;
    orow[j] = Prow[km];
  }
}

// ---------------- combine + LN1 ----------------
__global__ __launch_bounds__(64) void combine_ln1_kernel(const float* __restrict__ x,
    const hbf* __restrict__ nx1c, const hbf* __restrict__ nx2c,
    const int* __restrict__ idxT, const int* __restrict__ idxC,
    const float* __restrict__ g, const float* __restrict__ be,
    float* __restrict__ xln, hbf* __restrict__ abf)
{
  const int r = blockIdx.x;                  // (b,l,c)
  const int lane = threadIdx.x;
  const int b = r / (L_ * C_);
  const int rem = r % (L_ * C_);
  const int l = rem / C_, c = rem % C_;
  const int pt = c * B_ + b;
  const int qm = (l == 0) ? 0 : idxT[pt * N_ + l - 1] + 1;
  const int kcm = idxC[b * C_ + c];
  const hbf* n1 = nx1c + ((size_t)pt * 21 + qm) * 512;
  const hbf* n2 = nx2c + (((size_t)(b * L_ + l)) * 10 + kcm) * 512;
  const size_t o1 = (size_t)r * D_;
  float vv[8];
  #pragma unroll
  for (int u = 0; u < 8; ++u) {
    int d = lane + u * 64;
    vv[u] = x[o1 + d] + bf2f(n1[d]) * bf2f(n2[d]);
  }
  float s = 0.f;
  #pragma unroll
  for (int u = 0; u < 8; ++u) s += vv[u];
  s = waveAllSum(s);
  float mean = s / (float)D_;
  float qq = 0.f;
  #pragma unroll
  for (int u = 0; u < 8; ++u) { float dd = vv[u] - mean; qq = fmaf(dd, dd, qq); }
  qq = waveAllSum(qq);
  float denom = sqrtf(qq / (float)D_ + 1e-5f);
  #pragma unroll
  for (int u = 0; u < 8; ++u) {
    int d = lane + u * 64;
    float o = (vv[u] - mean) / denom * g[d] + be[d];
    xln[o1 + d] = o;
    abf[o1 + d] = __float2bfloat16(o);
  }
}

__global__ __launch_bounds__(64) void ln2_kernel(const float* __restrict__ xln, const hbf* __restrict__ ypre,
    const float* __restrict__ g, const float* __restrict__ be, float* __restrict__ out)
{
  const int r = blockIdx.x;
  const int lane = threadIdx.x;
  const size_t o1 = (size_t)r * D_;
  float vv[8];
  #pragma unroll
  for (int u = 0; u < 8; ++u) { int d = lane + u * 64; vv[u] = xln[o1 + d] + bf2f(ypre[o1 + d]); }
  float s = 0.f;
  #pragma unroll
  for (int u = 0; u < 8; ++u) s += vv[u];
  s = waveAllSum(s);
  float mean = s / (float)D_;
  float qq = 0.f;
  #pragma unroll
  for (int u = 0; u < 8; ++u) { float dd = vv[u] - mean; qq = fmaf(dd, dd, qq); }
  qq = waveAllSum(qq);
  float denom = sqrtf(qq / (float)D_ + 1e-5f);
  #pragma unroll
  for (int u = 0; u < 8; ++u) {
    int d = lane + u * 64;
    out[o1 + d] = (vv[u] - mean) / denom * g[d] + be[d];
  }
}

// ---------------- host ----------------
extern "C" void kernel_launch(void* const* d_in, const int* in_sizes, int n_in,
                              void* d_out, int out_size, void* d_ws, size_t ws_size,
                              hipStream_t stream)
{
  const float* x   = (const float*)d_in[0];
  const float* W[12];
  for (int i = 0; i < 12; ++i) W[i] = (const float*)d_in[1 + i];
  const float* b3  = (const float*)d_in[10];
  const float* b4  = (const float*)d_in[12];
  const float* g1  = (const float*)d_in[13];
  const float* be1 = (const float*)d_in[14];
  const float* g2  = (const float*)d_in[15];
  const float* be2 = (const float*)d_in[16];

  float* outY = (float*)d_out;
  float* outA = outY + (size_t)ROWS_ * D_;

  char* ws = (char*)d_ws;
  size_t off = 0;
  auto alloc = [&](size_t bytes){ size_t cur = off; off += (bytes + 255) & ~(size_t)255; return cur; };

  const size_t oAB  = alloc((size_t)MPAD_ * D_ * 2);   // xln bf16 for MLP
  const size_t oQ   = alloc((size_t)ROWS_ * D_ * 2);   // hbufF region (4 planes, 181MB)
  const size_t oK   = alloc((size_t)ROWS_ * D_ * 2);
  const size_t oV   = alloc((size_t)ROWS_ * D_ * 2);
  const size_t oNX2 = alloc((size_t)ROWS_ * D_ * 2);
  const size_t oR1  = alloc((size_t)ROWS_ * D_ * 4);   // distT -> xln f32
  const size_t oR2  = alloc(62000000);                 // merged/compact -> ypreBF
  const size_t oWT  = alloc(8 * 524288 + 2 * 2097152);
  const size_t oIT  = alloc(44000 * 4);
  const size_t oIC  = alloc(220 * 4);
  const size_t oNWT = alloc(220 * KT_ * 4);
  const size_t oNWC = alloc(B_ * KC_ * 4);
  const size_t oCTT = alloc(220 * KT_ * 4);
  const size_t oCTC = alloc(B_ * KC_ * 4);
  const size_t oX2T = alloc(44000 * 4);
  const size_t oX2C = alloc(220 * 4);
  const size_t oDET = alloc(44000 * 4);
  const size_t oDEC = alloc(220 * 4);
  const size_t oSCT = alloc(44000 * 4);
  const size_t oSCC = alloc(220 * 4);
  const size_t oDMT = alloc(220 * 4);
  const size_t oDMC = alloc(B_ * 4);
  const size_t oPT  = alloc(44000 * 4);
  const size_t oPC  = alloc(220 * 4);
  const size_t oDC  = alloc((size_t)B_ * C_ * C_ * 4);
  (void)ws_size; (void)in_sizes; (void)n_in; (void)out_size;

  hbf*   Abuf   = (hbf*)(ws + oAB);
  hbf*   hbufF  = (hbf*)(ws + oQ);
  float* distT  = (float*)(ws + oR1);
  float* xlnF   = (float*)(ws + oR1);
  float* mergedT = (float*)(ws + oR2);
  float* mergedC = (float*)(ws + oR2 + 40000000);
  hbf*   XCc    = (hbf*)(ws + oR2 + 9100000);
  hbf*   Qc2    = (hbf*)(ws + oR2 + 17400000);
  hbf*   Kc2    = Qc2 + (size_t)MCCP_ * 512;
  hbf*   Vc2    = Kc2 + (size_t)MCCP_ * 512;
  hbf*   Oc2    = (hbf*)(ws + oR2 + 42300000);
  hbf*   nx2c   = (hbf*)(ws + oR2 + 50600000);
  hbf*   XAc    = (hbf*)(ws + oR2 + 9100000);
  hbf*   Qc1    = (hbf*)(ws + oR2 + 14000000);
  hbf*   Kc1    = Qc1 + (size_t)MTCP_ * 512;
  hbf*   Vc1    = Kc1 + (size_t)MTCP_ * 512;
  hbf*   Oc1    = (hbf*)(ws + oR2 + 28700000);
  hbf*   nx1c   = (hbf*)(ws + oR2 + 33600000);
  float* PcG    = (float*)(ws + oR2 + 38500000);
  hbf*   ypreBF = (hbf*)(ws + oR2);
  hbf*   WT[8];
  for (int i = 0; i < 8; ++i) WT[i] = (hbf*)(ws + oWT + (size_t)i * 524288);
  hbf*   W3T = (hbf*)(ws + oWT + 4194304);
  hbf*   W4T = (hbf*)(ws + oWT + 6291456);
  int* idxT = (int*)(ws + oIT);
  int* idxC = (int*)(ws + oIC);
  float* nwT = (float*)(ws + oNWT);
  float* nwC = (float*)(ws + oNWC);
  int* cntT = (int*)(ws + oCTT);
  int* cntC = (int*)(ws + oCTC);
  float* x2T = (float*)(ws + oX2T);
  float* x2C = (float*)(ws + oX2C);
  float* densT = (float*)(ws + oDET);
  float* densC = (float*)(ws + oDEC);
  float* scoreT = (float*)(ws + oSCT);
  float* scoreC = (float*)(ws + oSCC);
  unsigned* dmaxT = (unsigned*)(ws + oDMT);
  unsigned* dmaxC = (unsigned*)(ws + oDMC);
  float* pertT = (float*)(ws + oPT);
  float* pertC = (float*)(ws + oPC);
  float* distC = (float*)(ws + oDC);

  size_t maskOff = (size_t)ROWS_ * D_ + (size_t)B_ * C_ * L_ * L_;
  (void)hipMemsetAsync((char*)d_out + maskOff * sizeof(float), 0,
                 ((size_t)B_ * C_ * L_ * L_ + ROWS_) * sizeof(float), stream);
  (void)hipMemsetAsync(ws + oDMT, 0, 220 * 4, stream);
  (void)hipMemsetAsync(ws + oDMC, 0, B_ * 4, stream);

  for (int i = 0; i < 8; ++i)
    transp_kernel<<<dim3(16, 16), 256, 0, stream>>>(W[i], WT[i], 512, 512);
  transp_kernel<<<dim3(64, 16), 256, 0, stream>>>(W[8],  W3T, 512, 2048);
  transp_kernel<<<dim3(16, 64), 256, 0, stream>>>(W[10], W4T, 2048, 512);

  // P1: RNG + temporal clustering
  pert_kernel<<<173, 256, 0, stream>>>(pertT, pertC);
  x2_kernel<<<11000, 256, 0, stream>>>(x, x2T, 44000, N_, 0);
  dist64_kernel<<<dim3(10, 220), 256, 0, stream>>>(x, x2T, distT, dmaxT, N_, 4, 0);
  knn_density_kernel<<<11000, 256, 0, stream>>>(distT, pertT, densT, 44000, N_, 20, 0);
  dparent_score_kernel<<<11000, 256, 0, stream>>>(distT, densT, dmaxT, scoreT, 44000, N_);
  seeds_assign_kernel<<<220, 256, 0, stream>>>(scoreT, distT, idxT, nwT, cntT, N_, KT_);
  merge_t_kernel<<<dim3(4, 220), 128, 0, stream>>>(x, idxT, nwT, mergedT);

  // P2: channel clustering
  x2_kernel<<<55, 256, 0, stream>>>(x, x2C, 220, C_, 1);
  dist64_kernel<<<dim3(1, 4), 256, 0, stream>>>(x, x2C, distC, dmaxC, C_, 1, 1);
  knn_density_kernel<<<55, 256, 0, stream>>>(distC, pertC, densC, 220, C_, 5, 1);
  dparent_score_kernel<<<55, 256, 0, stream>>>(distC, densC, dmaxC, scoreC, 220, C_);
  seeds_assign_kernel<<<4, 256, 0, stream>>>(scoreC, distC, idxC, nwC, cntC, C_, KC_);
  merge_c_kernel<<<dim3(804, 4), 128, 0, stream>>>(x, idxC, nwC, mergedC);

  // P3: channel attention (compact, 8040 rows)
  cast_xcc_bf<<<2016, 256, 0, stream>>>(mergedC, XCc);
  gemm_mfma<hbf, 4><<<dim3(12, 63), 256, 0, stream>>>(XCc, WT[4], Qc2, nullptr, MCC_, 1536, 512, (size_t)MCCP_ * 512);
  attn_compact_c<<<804, 256, 0, stream>>>(Qc2, Kc2, Vc2, cntC, Oc2);
  gemm_mfma<hbf, 0><<<dim3(4, 63), 256, 0, stream>>>(Oc2, WT[7], nx2c, nullptr, MCC_, 512, 512, 0);

  // P4: temporal attention (compact, 4620 rows)
  build_xac_bf<<<1184, 256, 0, stream>>>(x, mergedT, XAc);
  gemm_mfma<hbf, 4><<<dim3(12, 37), 256, 0, stream>>>(XAc, WT[0], Qc1, nullptr, MTC_, 1536, 512, (size_t)MTCP_ * 512);
  attn_compact_t<<<220, 256, 0, stream>>>(Qc1, Kc1, Vc1, cntT, PcG, Oc1);
  expand_attn<<<11055, 256, 0, stream>>>(PcG, idxT, outA);
  gemm_mfma<hbf, 0><<<dim3(4, 37), 256, 0, stream>>>(Oc1, WT[3], nx1c, nullptr, MTC_, 512, 512, 0);

  // P5: combine + LN1 (writes xln f32 + bf16 copy)
  combine_ln1_kernel<<<ROWS_, 64, 0, stream>>>(x, nx1c, nx2c, idxT, idxC, g1, be1, xlnF, Abuf);

  // P6: MLP unchunked (wide 128x256 GEMMs) + LN2
  gemm_mfma_w<hbf, 2><<<dim3(8, 346), 256, 0, stream>>>(Abuf, W3T, hbufF, b3, ROWS_, 2048, 512);
  gemm_mfma_w<hbf, 1><<<dim3(2, 346), 256, 0, stream>>>(hbufF, W4T, ypreBF, b4, ROWS_, 512, 2048);
  ln2_kernel<<<ROWS_, 64, 0, stream>>>(xlnF, ypreBF, g2, be2, outY);
}

// Round 15
// 1085.902 us; speedup vs baseline: 1.2914x; 1.2914x over previous
//
#include <hip/hip_runtime.h>
#include <hip/hip_bf16.h>

#define B_ 4
#define L_ 201
#define C_ 55
#define D_ 512
#define F_ 2048
#define N_ 200
#define KT_ 20
#define KC_ 10
#define ROWS_ 44220          // B*L*C
#define CD_ (C_*D_)
#define MPAD_ 44416          // 347*128, padded M for MFMA A-tiles
#define MTC_ 4620            // 220*21 compact temporal rows
#define MTCP_ 4736           // 37*128
#define MCC_ 8040            // 804*10 compact channel rows
#define MCCP_ 8064           // 63*128

using hbf = __hip_bfloat16;
typedef float f32x4 __attribute__((ext_vector_type(4)));
typedef short s16x8 __attribute__((ext_vector_type(8)));

static __device__ __forceinline__ float bf2f(hbf v){ return __bfloat162float(v); }
static __device__ __forceinline__ void cvtS(float* p, float v){ *p = v; }
static __device__ __forceinline__ void cvtS(hbf* p, float v){ *p = __float2bfloat16(v); }

#define GL2LDS16(g, l) __builtin_amdgcn_global_load_lds( \
    (const __attribute__((address_space(1))) void*)(g),  \
    (__attribute__((address_space(3))) void*)(l), 16, 0, 0)

static __device__ __forceinline__ float waveAllSum(float v){
  #pragma unroll
  for (int off = 32; off; off >>= 1) v += __shfl_xor(v, off);
  return v;
}

// ---------------- Threefry-2x32 (exact JAX semantics) ----------------
static __device__ __forceinline__ void tf2x32(unsigned k0, unsigned k1, unsigned x0, unsigned x1,
                                              unsigned &o0, unsigned &o1)
{
  const unsigned k2 = k0 ^ k1 ^ 0x1BD11BDAu;
  unsigned v0 = x0 + k0, v1 = x1 + k1;
  #define TFR(r) { v0 += v1; v1 = (v1 << (r)) | (v1 >> (32 - (r))); v1 ^= v0; }
  TFR(13) TFR(15) TFR(26) TFR(6)
  v0 += k1; v1 += k2 + 1u;
  TFR(17) TFR(29) TFR(16) TFR(24)
  v0 += k2; v1 += k0 + 2u;
  TFR(13) TFR(15) TFR(26) TFR(6)
  v0 += k0; v1 += k1 + 3u;
  TFR(17) TFR(29) TFR(16) TFR(24)
  v0 += k1; v1 += k2 + 4u;
  TFR(13) TFR(15) TFR(26) TFR(6)
  v0 += k2; v1 += k0 + 5u;
  #undef TFR
  o0 = v0; o1 = v1;
}
static __device__ __forceinline__ float tfu(unsigned bits){
  return __uint_as_float((bits >> 9) | 0x3f800000u) - 1.0f;
}
static __device__ __forceinline__ unsigned tf_flat(unsigned k0, unsigned k1, int m, int H){
  unsigned o0, o1;
  if (m < H) { tf2x32(k0, k1, (unsigned)m, (unsigned)(H + m), o0, o1); return o0; }
  tf2x32(k0, k1, (unsigned)(m - H), (unsigned)m, o0, o1); return o1;
}

__global__ void pert_kernel(float* __restrict__ pertT, float* __restrict__ pertC)
{
  int t = blockIdx.x * blockDim.x + threadIdx.x;
  if (t < 55 * 800) {
    int c = t / 800, j = t % 800;
    unsigned kc0 = tf_flat(0u, 42u, 2 * c, 55);
    unsigned kc1 = tf_flat(0u, 42u, 2 * c + 1, 55);
    unsigned bits = tf_flat(kc0, kc1, j, 400);
    pertT[t] = tfu(bits) * 1e-6f;
  } else if (t < 55 * 800 + 220) {
    int j = t - 55 * 800;
    unsigned bits = tf_flat(0u, 7u, j, 110);
    pertC[j] = tfu(bits) * 1e-6f;
  }
}

// ---------------- clustering ----------------
static __device__ __forceinline__ size_t pt_base(int mode, int p, int i){
  if (mode == 0) { int c = p / B_, b = p % B_; return ((size_t)(b * L_ + 1 + i) * C_ + c) * D_; }
  return ((size_t)(p * L_) * C_ + i) * D_;
}

__global__ __launch_bounds__(256) void x2_kernel(const float* __restrict__ x, float* __restrict__ x2,
                                                 int nrows, int npts, int mode)
{
  int row = blockIdx.x * 4 + (threadIdx.x >> 6);
  int lane = threadIdx.x & 63;
  if (row >= nrows) return;
  int p = row / npts, i = row % npts;
  const float* px = x + pt_base(mode, p, i);
  float s = 0.f;
  #pragma unroll
  for (int u = 0; u < 8; ++u) { float v = px[lane + u * 64]; s = fmaf(v, v, s); }
  s = waveAllSum(s);
  if (lane == 0) x2[row] = s;
}

// symmetric-pair 64x64-tile distance kernel, BK=32; mirror via LDS transpose OVERLAID on As/Bs
__global__ __launch_bounds__(256) void dist64_kernel(const float* __restrict__ x, const float* __restrict__ x2,
    float* __restrict__ dist, unsigned* __restrict__ dmax, int npts, int nt, int mode)
{
  const int p = blockIdx.y;
  int idx = blockIdx.x;
  int ti = 0;
  while (idx >= nt - ti) { idx -= nt - ti; ++ti; }
  const int tj = ti + idx;
  const int i0 = ti * 64, j0 = tj * 64;
  const int tid = threadIdx.x;
  const int tx = tid & 15, ty = tid >> 4;
  const int ar = tid >> 2, ak = (tid & 3) * 8;
  __shared__ __align__(16) char dsm[17408];     // As[32][68] | Bs[32][68]  -> reused as Ts[64][65]
  float (*As)[68] = (float(*)[68])dsm;
  float (*Bs)[68] = (float(*)[68])(dsm + 8704);
  float (*Ts)[65] = (float(*)[65])dsm;
  __shared__ unsigned bmax;
  if (tid == 0) bmax = 0u;
  int ia = i0 + ar; if (ia >= npts) ia = npts - 1;
  int jb = j0 + ar; if (jb >= npts) jb = npts - 1;
  const size_t baseA = pt_base(mode, p, ia);
  const size_t baseB = pt_base(mode, p, jb);
  float acc[4][4] = {};
  for (int k0 = 0; k0 < D_; k0 += 32) {
    float4 la0 = *(const float4*)&x[baseA + k0 + ak];
    float4 la1 = *(const float4*)&x[baseA + k0 + ak + 4];
    float4 lb0 = *(const float4*)&x[baseB + k0 + ak];
    float4 lb1 = *(const float4*)&x[baseB + k0 + ak + 4];
    __syncthreads();
    As[ak + 0][ar] = la0.x; As[ak + 1][ar] = la0.y; As[ak + 2][ar] = la0.z; As[ak + 3][ar] = la0.w;
    As[ak + 4][ar] = la1.x; As[ak + 5][ar] = la1.y; As[ak + 6][ar] = la1.z; As[ak + 7][ar] = la1.w;
    Bs[ak + 0][ar] = lb0.x; Bs[ak + 1][ar] = lb0.y; Bs[ak + 2][ar] = lb0.z; Bs[ak + 3][ar] = lb0.w;
    Bs[ak + 4][ar] = lb1.x; Bs[ak + 5][ar] = lb1.y; Bs[ak + 6][ar] = lb1.z; Bs[ak + 7][ar] = lb1.w;
    __syncthreads();
    #pragma unroll
    for (int kk = 0; kk < 32; ++kk) {
      float4 av = *(const float4*)&As[kk][ty * 4];
      float4 bv = *(const float4*)&Bs[kk][tx * 4];
      float a4[4] = {av.x, av.y, av.z, av.w};
      float b4[4] = {bv.x, bv.y, bv.z, bv.w};
      #pragma unroll
      for (int u = 0; u < 4; ++u)
        #pragma unroll
        for (int v = 0; v < 4; ++v) acc[u][v] = fmaf(a4[u], b4[v], acc[u][v]);
    }
  }
  __syncthreads();
  unsigned lmax = 0u;
  #pragma unroll
  for (int u = 0; u < 4; ++u) {
    int i = i0 + ty * 4 + u;
    #pragma unroll
    for (int v = 0; v < 4; ++v) {
      int j = j0 + tx * 4 + v;
      if (i < npts && j < npts) {
        float d2 = x2[p * npts + i] + x2[p * npts + j] - 2.0f * acc[u][v];
        float dv = sqrtf(fmaxf(d2, 0.0f)) / 22.627416997969522f;
        dist[((size_t)p * npts + i) * npts + j] = dv;
        Ts[tx * 4 + v][ty * 4 + u] = dv;
        unsigned b = __float_as_uint(dv);
        if (b > lmax) lmax = b;
      }
    }
  }
  atomicMax(&bmax, lmax);
  __syncthreads();
  if (ti != tj) {
    const int jj = tid >> 2, iiB = (tid & 3) * 16;
    int gj = j0 + jj;
    if (gj < npts) {
      float* drow = dist + ((size_t)p * npts + gj) * npts + i0;
      #pragma unroll
      for (int v = 0; v < 16; ++v) {
        int ii = iiB + v;
        if (i0 + ii < npts) drow[ii] = Ts[jj][ii];
      }
    }
  }
  if (tid == 0) atomicMax(&dmax[p], bmax);
}

__global__ __launch_bounds__(256) void knn_density_kernel(const float* __restrict__ dist,
    const float* __restrict__ pert, float* __restrict__ density, int nrows, int npts, int kk, int mode)
{
  int row = blockIdx.x * 4 + (threadIdx.x >> 6);
  int lane = threadIdx.x & 63;
  if (row >= nrows) return;
  const float INF = __int_as_float(0x7f800000);
  const float* dr = dist + (size_t)row * npts;
  float vals[4];
  #pragma unroll
  for (int u = 0; u < 4; ++u) { int j = lane + u * 64; vals[u] = (j < npts) ? dr[j] : INF; }
  float acc = 0.f;
  for (int it = 0; it < kk; ++it) {
    float m = fminf(fminf(vals[0], vals[1]), fminf(vals[2], vals[3]));
    #pragma unroll
    for (int off = 32; off; off >>= 1) m = fminf(m, __shfl_xor(m, off));
    acc += m * m;
    bool has = (vals[0] == m) || (vals[1] == m) || (vals[2] == m) || (vals[3] == m);
    unsigned long long bal = __ballot(has);
    int fl = __ffsll(bal) - 1;
    if (lane == fl) {
      if (vals[0] == m) vals[0] = INF;
      else if (vals[1] == m) vals[1] = INF;
      else if (vals[2] == m) vals[2] = INF;
      else vals[3] = INF;
    }
  }
  if (lane == 0) {
    float mean = acc / (float)kk;
    int pidx;
    if (mode == 0) { int p = row / npts; int i = row - p * npts; int c = p / B_, b = p % B_; pidx = c * 800 + b * 200 + i; }
    else pidx = row;
    density[row] = expf(-mean) + pert[pidx];
  }
}

// wave-per-row d_parent + score
__global__ __launch_bounds__(256) void dparent_score_kernel(const float* __restrict__ dist,
    const float* __restrict__ density, const unsigned* __restrict__ dmax, float* __restrict__ score,
    int nrows, int npts)
{
  int row = blockIdx.x * 4 + (threadIdx.x >> 6);
  int lane = threadIdx.x & 63;
  if (row >= nrows) return;
  int p = row / npts;
  float di = density[row];
  const float* dr = dist + (size_t)row * npts;
  const float* de = density + (size_t)p * npts;
  float mn = __int_as_float(0x7f800000);
  #pragma unroll
  for (int u = 0; u < 4; ++u) {
    int j = lane + u * 64;
    if (j < npts && de[j] > di) mn = fminf(mn, dr[j]);
  }
  #pragma unroll
  for (int off = 32; off; off >>= 1) mn = fminf(mn, __shfl_xor(mn, off));
  if (lane == 0) {
    float dp = fminf(mn, __uint_as_float(dmax[p]));
    score[row] = dp * di;
  }
}

// seeds + assignment; also emits raw cluster counts
__global__ __launch_bounds__(256) void seeds_assign_kernel(const float* __restrict__ score,
    const float* __restrict__ dist, int* __restrict__ idx, float* __restrict__ nw,
    int* __restrict__ cntOut, int npts, int K)
{
  const int p = blockIdx.x;
  const int t = threadIdx.x;
  __shared__ float s[N_];
  __shared__ int seeds[KT_];
  __shared__ int lidx[N_];
  __shared__ int cnt[KT_];
  for (int e = t; e < npts; e += 256) s[e] = score[(size_t)p * npts + e];
  if (t < K) cnt[t] = 0;
  __syncthreads();
  if (t == 0) {
    for (int k2 = 0; k2 < K; ++k2) {
      float best = -1.f; int bi = 0;
      for (int n = 0; n < npts; ++n) if (s[n] > best) { best = s[n]; bi = n; }
      seeds[k2] = bi; s[bi] = -2.f;
    }
  }
  __syncthreads();
  for (int e = t; e < npts; e += 256) {
    float best = __int_as_float(0x7f800000); int bk = 0;
    for (int k2 = 0; k2 < K; ++k2) {
      float dv = dist[((size_t)p * npts + seeds[k2]) * npts + e];
      if (dv < best) { best = dv; bk = k2; }
    }
    lidx[e] = bk;
  }
  __syncthreads();
  if (t < K) lidx[seeds[t]] = t;
  __syncthreads();
  for (int e = t; e < npts; e += 256) atomicAdd(&cnt[lidx[e]], 1);
  __syncthreads();
  for (int e = t; e < npts; e += 256) idx[(size_t)p * npts + e] = lidx[e];
  if (t < K) {
    nw[p * K + t] = 1.0f / ((float)cnt[t] + 1e-6f);
    cntOut[p * K + t] = cnt[t];
  }
}

__global__ __launch_bounds__(128) void merge_t_kernel(const float* __restrict__ x, const int* __restrict__ idx,
    const float* __restrict__ nw, float* __restrict__ merged)
{
  const int dc = blockIdx.x;
  const int p  = blockIdx.y;
  const int c = p / B_, b = p % B_;
  const int t = threadIdx.x;
  __shared__ float acc[KT_][128];
  __shared__ int li[N_];
  __shared__ float lw[KT_];
  for (int e = t; e < N_; e += 128) li[e] = idx[p * N_ + e];
  if (t < KT_) lw[t] = nw[p * KT_ + t];
  #pragma unroll
  for (int k2 = 0; k2 < KT_; ++k2) acc[k2][t] = 0.f;
  __syncthreads();
  const float* px = x + ((size_t)(b * L_ + 1) * C_ + c) * D_ + dc * 128 + t;
  for (int n = 0; n < N_; ++n) {
    int kt = li[n];
    acc[kt][t] += px[(size_t)n * CD_] * lw[kt];
  }
  __syncthreads();
  for (int k2 = 0; k2 < KT_; ++k2)
    merged[((size_t)p * KT_ + k2) * D_ + dc * 128 + t] = acc[k2][t];
}

__global__ __launch_bounds__(128) void merge_c_kernel(const float* __restrict__ x, const int* __restrict__ idxc,
    const float* __restrict__ nwc, float* __restrict__ merged)
{
  const int bl = blockIdx.x;
  const int dc = blockIdx.y;
  const int b = bl / L_, l = bl % L_;
  const int t = threadIdx.x;
  __shared__ float acc[KC_][128];
  __shared__ int li[C_];
  __shared__ float lw[KC_];
  if (t < C_) li[t] = idxc[b * C_ + t];
  if (t < KC_) lw[t] = nwc[b * KC_ + t];
  #pragma unroll
  for (int k2 = 0; k2 < KC_; ++k2) acc[k2][t] = 0.f;
  __syncthreads();
  const float* px = x + ((size_t)(b * L_ + l) * C_) * D_ + dc * 128 + t;
  for (int cc = 0; cc < C_; ++cc) {
    int kc = li[cc];
    acc[kc][t] += px[(size_t)cc * D_] * lw[kc];
  }
  __syncthreads();
  for (int k2 = 0; k2 < KC_; ++k2)
    merged[((size_t)(b * L_ + l) * KC_ + k2) * D_ + dc * 128 + t] = acc[k2][t];
}

// ---------------- compact A-matrix builders ----------------
__global__ void build_xac_bf(const float* __restrict__ ori, const float* __restrict__ merged,
                             hbf* __restrict__ xa)
{
  int e = blockIdx.x * 256 + threadIdx.x;
  if (e >= MTCP_ * 64) return;
  int r = e >> 6, q8 = e & 63;
  hbf tmp[8];
  if (r < MTC_) {
    int p = r / 21, ks = r % 21;
    const float* sp;
    if (ks == 0) {
      int c = p / B_, b = p % B_;
      sp = ori + ((size_t)(b * L_) * C_ + c) * D_ + q8 * 8;
    } else {
      sp = merged + ((size_t)p * KT_ + ks - 1) * D_ + q8 * 8;
    }
    #pragma unroll
    for (int u = 0; u < 8; ++u) tmp[u] = __float2bfloat16(sp[u]);
  } else {
    #pragma unroll
    for (int u = 0; u < 8; ++u) tmp[u] = __float2bfloat16(0.f);
  }
  *(uint4*)(xa + (size_t)r * D_ + q8 * 8) = *(uint4*)tmp;
}

__global__ void cast_xcc_bf(const float* __restrict__ merged, hbf* __restrict__ xc)
{
  int e = blockIdx.x * 256 + threadIdx.x;
  if (e >= MCCP_ * 64) return;
  int r = e >> 6, q8 = e & 63;
  hbf tmp[8];
  if (r < MCC_) {
    const float* sp = merged + (size_t)r * D_ + q8 * 8;
    #pragma unroll
    for (int u = 0; u < 8; ++u) tmp[u] = __float2bfloat16(sp[u]);
  } else {
    #pragma unroll
    for (int u = 0; u < 8; ++u) tmp[u] = __float2bfloat16(0.f);
  }
  *(uint4*)(xc + (size_t)r * D_ + q8 * 8) = *(uint4*)tmp;
}

// ---------------- weight transpose+cast ----------------
__global__ __launch_bounds__(256) void transp_kernel(const float* __restrict__ src, hbf* __restrict__ dst,
                                                     int K, int N)
{
  __shared__ float tile[32][33];
  const int t = threadIdx.x;
  const int tx = t & 31, ry = t >> 5;
  const int n0 = blockIdx.x * 32, k0 = blockIdx.y * 32;
  #pragma unroll
  for (int r = 0; r < 4; ++r)
    tile[ry + r * 8][tx] = src[(size_t)(k0 + ry + r * 8) * N + n0 + tx];
  __syncthreads();
  #pragma unroll
  for (int r = 0; r < 4; ++r)
    dst[(size_t)(n0 + ry + r * 8) * K + k0 + tx] = __float2bfloat16(tile[tx][ry + r * 8]);
}

// ---------------- MFMA GEMM 128x128 via global_load_lds + XOR swizzle ----------------
// EPI: 0=store, 1=+bias, 2=+bias+GELU, 4=splitN/512 planes with stride pstride
template<typename TC, int EPI>
__global__ __launch_bounds__(256) void gemm_mfma(const hbf* __restrict__ A, const hbf* __restrict__ BT,
    TC* __restrict__ Cp, const float* __restrict__ bias, int M, int N, int K, size_t pstride)
{
  __shared__ hbf As[128 * 64];
  __shared__ hbf Bs[128 * 64];
  const int tid = threadIdx.x;
  const int nwg = gridDim.x * gridDim.y;
  const int bid = blockIdx.y * gridDim.x + blockIdx.x;
  const int q = nwg >> 3, rr = nwg & 7;
  const int xcd = bid & 7, loc = bid >> 3;
  const int swzid = (xcd < rr) ? (xcd * (q + 1) + loc) : (rr * (q + 1) + (xcd - rr) * q + loc);
  const int row0 = (swzid / gridDim.x) * 128, col0 = (swzid % gridDim.x) * 128;
  const int lane = tid & 63, wid = tid >> 6;
  const int wm = wid & 1, wn = wid >> 1;
  const int lr = lane & 15, lk8 = (lane >> 4) * 8;
  const int srow = wid * 32 + (lane >> 3);
  const int scol = ((lane & 7) ^ (lane >> 3)) * 8;
  const hbf* agp = A + (size_t)(row0 + srow) * K + scol;
  const hbf* bgp = BT + (size_t)(col0 + srow) * K + scol;
  hbf* asw = As + wid * 32 * 64;
  hbf* bsw = Bs + wid * 32 * 64;
  const int swz = (lr & 7) * 8;
  f32x4 acc[4][4] = {};
  for (int k0 = 0; k0 < K; k0 += 64) {
    __syncthreads();
    #pragma unroll
    for (int t = 0; t < 4; ++t) {
      GL2LDS16(agp + k0 + (size_t)t * 8 * K, asw + t * 8 * 64);
      GL2LDS16(bgp + k0 + (size_t)t * 8 * K, bsw + t * 8 * 64);
    }
    asm volatile("s_waitcnt vmcnt(0)" ::: "memory");
    __syncthreads();
    #pragma unroll
    for (int ks = 0; ks < 64; ks += 32) {
      s16x8 af[4], bfr[4];
      #pragma unroll
      for (int i = 0; i < 4; ++i)
        af[i] = *(const s16x8*)&As[(wm * 64 + i * 16 + lr) * 64 + ((ks + lk8) ^ swz)];
      #pragma unroll
      for (int j = 0; j < 4; ++j)
        bfr[j] = *(const s16x8*)&Bs[(wn * 64 + j * 16 + lr) * 64 + ((ks + lk8) ^ swz)];
      #pragma unroll
      for (int i = 0; i < 4; ++i)
        #pragma unroll
        for (int j = 0; j < 4; ++j)
          acc[i][j] = __builtin_amdgcn_mfma_f32_16x16x32_bf16(af[i], bfr[j], acc[i][j], 0, 0, 0);
    }
  }
  #pragma unroll
  for (int i = 0; i < 4; ++i) {
    #pragma unroll
    for (int r = 0; r < 4; ++r) {
      int row = row0 + wm * 64 + i * 16 + (lane >> 4) * 4 + r;
      if (row < M) {
        #pragma unroll
        for (int j = 0; j < 4; ++j) {
          int col = col0 + wn * 64 + j * 16 + lr;
          float val = acc[i][j][r];
          if (EPI == 1 || EPI == 2) val += bias[col];
          if (EPI == 2) val = 0.5f * val * (1.f + erff(val * 0.70710678118654752f));
          if (EPI == 4) {
            cvtS(&Cp[(size_t)(col >> 9) * pstride + (size_t)row * 512 + (col & 511)], val);
          } else {
            cvtS(&Cp[(size_t)row * N + col], val);
          }
        }
      }
    }
  }
}

// ---------------- compact temporal attention ----------------
__global__ __launch_bounds__(256) void attn_compact_t(const hbf* __restrict__ Qc, const hbf* __restrict__ Kc,
    const hbf* __restrict__ Vc, const int* __restrict__ cntT, float* __restrict__ PcG, hbf* __restrict__ Oc)
{
  const int p = blockIdx.x;
  const int t = threadIdx.x;
  __shared__ hbf Qs[21 * 512];
  __shared__ hbf Ks[21 * 512];
  __shared__ float Ss[21][22];
  __shared__ float Pw[21][22];
  __shared__ float cnt[21];
  for (int e = t; e < 21 * 64; e += 256) {
    ((uint4*)Qs)[e] = ((const uint4*)(Qc + (size_t)p * 21 * 512))[e];
    ((uint4*)Ks)[e] = ((const uint4*)(Kc + (size_t)p * 21 * 512))[e];
  }
  if (t < 21) cnt[t] = (t == 0) ? 1.0f : (float)cntT[p * KT_ + t - 1];
  __syncthreads();
  for (int pr = t; pr < 441; pr += 256) {
    int qq = pr / 21, kk = pr % 21;
    float s = 0.f;
    #pragma unroll 8
    for (int ch = 0; ch < 64; ++ch) {
      union { s16x8 v; hbf e[8]; } qa, kb;
      qa.v = ((const s16x8*)Qs)[qq * 64 + ch];
      kb.v = ((const s16x8*)Ks)[kk * 64 + ch];
      #pragma unroll
      for (int u = 0; u < 8; ++u)
        s = fmaf(bf2f(qa.e[u]), bf2f(kb.e[u]), s);
    }
    Ss[qq][kk] = s * 0.04419417382415922f;
  }
  __syncthreads();
  if (t < 21) {
    float mx = -3.4e38f;
    for (int kk = 0; kk < 21; ++kk) mx = fmaxf(mx, Ss[t][kk]);
    float den = 0.f;
    for (int kk = 0; kk < 21; ++kk) den += cnt[kk] * expf(Ss[t][kk] - mx);
    float inv = 1.0f / den;
    for (int kk = 0; kk < 21; ++kk) {
      float pc = expf(Ss[t][kk] - mx) * inv;
      Ss[t][kk] = pc;
      Pw[t][kk] = cnt[kk] * pc;
    }
  }
  __syncthreads();
  for (int e = t; e < 441; e += 256) PcG[(size_t)p * 441 + e] = Ss[e / 21][e % 21];
  for (int o = t; o < 21 * 512; o += 256) {
    int qq = o >> 9, d = o & 511;
    float s = 0.f;
    #pragma unroll
    for (int ks = 0; ks < 21; ++ks)
      s = fmaf(Pw[qq][ks], bf2f(Vc[((size_t)p * 21 + ks) * 512 + d]), s);
    Oc[((size_t)p * 21 + qq) * 512 + d] = __float2bfloat16(s);
  }
}

// ---------------- compact channel attention ----------------
__global__ __launch_bounds__(256) void attn_compact_c(const hbf* __restrict__ Qc, const hbf* __restrict__ Kc,
    const hbf* __restrict__ Vc, const int* __restrict__ cntC, hbf* __restrict__ Oc)
{
  const int bl = blockIdx.x;
  const int b = bl / L_;
  const int t = threadIdx.x;
  __shared__ hbf Qs[10 * 512];
  __shared__ hbf Ks[10 * 512];
  __shared__ float Ss[10][12];
  __shared__ float Pw[10][12];
  __shared__ float cnt[10];
  for (int e = t; e < 10 * 64; e += 256) {
    ((uint4*)Qs)[e] = ((const uint4*)(Qc + (size_t)bl * 10 * 512))[e];
    ((uint4*)Ks)[e] = ((const uint4*)(Kc + (size_t)bl * 10 * 512))[e];
  }
  if (t < 10) cnt[t] = (float)cntC[b * KC_ + t];
  __syncthreads();
  if (t < 100) {
    int qq = t / 10, kk = t % 10;
    float s = 0.f;
    #pragma unroll 8
    for (int ch = 0; ch < 64; ++ch) {
      union { s16x8 v; hbf e[8]; } qa, kb;
      qa.v = ((const s16x8*)Qs)[qq * 64 + ch];
      kb.v = ((const s16x8*)Ks)[kk * 64 + ch];
      #pragma unroll
      for (int u = 0; u < 8; ++u)
        s = fmaf(bf2f(qa.e[u]), bf2f(kb.e[u]), s);
    }
    Ss[qq][kk] = s * 0.04419417382415922f;
  }
  __syncthreads();
  if (t < 10) {
    float mx = -3.4e38f;
    for (int kk = 0; kk < 10; ++kk) mx = fmaxf(mx, Ss[t][kk]);
    float den = 0.f;
    for (int kk = 0; kk < 10; ++kk) den += cnt[kk] * expf(Ss[t][kk] - mx);
    float inv = 1.0f / den;
    for (int kk = 0; kk < 10; ++kk) Pw[t][kk] = cnt[kk] * expf(Ss[t][kk] - mx) * inv;
  }
  __syncthreads();
  for (int o = t; o < 10 * 512; o += 256) {
    int qq = o >> 9, d = o & 511;
    float s = 0.f;
    #pragma unroll
    for (int ks = 0; ks < 10; ++ks)
      s = fmaf(Pw[qq][ks], bf2f(Vc[((size_t)bl * 10 + ks) * 512 + d]), s);
    Oc[((size_t)bl * 10 + qq) * 512 + d] = __float2bfloat16(s);
  }
}

// ---------------- expand attn output ----------------
__global__ __launch_bounds__(256) void expand_attn(const float* __restrict__ PcG,
    const int* __restrict__ idxT, float* __restrict__ outA)
{
  const int r = blockIdx.x * 4 + (threadIdx.x >> 6);   // 220*201 rows in (b,c,l)
  const int lane = threadIdx.x & 63;
  const int b = r / (C_ * L_);
  const int rem = r % (C_ * L_);
  const int c = rem / L_, l = rem % L_;
  const int p = c * B_ + b;
  const int qm = (l == 0) ? 0 : idxT[p * N_ + l - 1] + 1;
  const float* Prow = PcG + ((size_t)p * 21 + qm) * 21;
  const int* im = idxT + (size_t)p * N_;
  float* orow = outA + (size_t)r * L_;
  for (int j = lane; j < L_; j += 64) {
    int km = (j == 0) ? 0 : im[j - 1] + 1;
    orow[j] = Prow[km];
  }
}

// ---------------- combine + LN1 ----------------
__global__ __launch_bounds__(64) void combine_ln1_kernel(const float* __restrict__ x,
    const hbf* __restrict__ nx1c, const hbf* __restrict__ nx2c,
    const int* __restrict__ idxT, const int* __restrict__ idxC,
    const float* __restrict__ g, const float* __restrict__ be,
    float* __restrict__ xln, hbf* __restrict__ abf)
{
  const int r = blockIdx.x;                  // (b,l,c)
  const int lane = threadIdx.x;
  const int b = r / (L_ * C_);
  const int rem = r % (L_ * C_);
  const int l = rem / C_, c = rem % C_;
  const int pt = c * B_ + b;
  const int qm = (l == 0) ? 0 : idxT[pt * N_ + l - 1] + 1;
  const int kcm = idxC[b * C_ + c];
  const hbf* n1 = nx1c + ((size_t)pt * 21 + qm) * 512;
  const hbf* n2 = nx2c + (((size_t)(b * L_ + l)) * 10 + kcm) * 512;
  const size_t o1 = (size_t)r * D_;
  float vv[8];
  #pragma unroll
  for (int u = 0; u < 8; ++u) {
    int d = lane + u * 64;
    vv[u] = x[o1 + d] + bf2f(n1[d]) * bf2f(n2[d]);
  }
  float s = 0.f;
  #pragma unroll
  for (int u = 0; u < 8; ++u) s += vv[u];
  s = waveAllSum(s);
  float mean = s / (float)D_;
  float qq = 0.f;
  #pragma unroll
  for (int u = 0; u < 8; ++u) { float dd = vv[u] - mean; qq = fmaf(dd, dd, qq); }
  qq = waveAllSum(qq);
  float denom = sqrtf(qq / (float)D_ + 1e-5f);
  #pragma unroll
  for (int u = 0; u < 8; ++u) {
    int d = lane + u * 64;
    float o = (vv[u] - mean) / denom * g[d] + be[d];
    xln[o1 + d] = o;
    abf[o1 + d] = __float2bfloat16(o);
  }
}

__global__ __launch_bounds__(64) void ln2_kernel(const float* __restrict__ xln, const hbf* __restrict__ ypre,
    const float* __restrict__ g, const float* __restrict__ be, float* __restrict__ out)
{
  const int r = blockIdx.x;
  const int lane = threadIdx.x;
  const size_t o1 = (size_t)r * D_;
  float vv[8];
  #pragma unroll
  for (int u = 0; u < 8; ++u) { int d = lane + u * 64; vv[u] = xln[o1 + d] + bf2f(ypre[o1 + d]); }
  float s = 0.f;
  #pragma unroll
  for (int u = 0; u < 8; ++u) s += vv[u];
  s = waveAllSum(s);
  float mean = s / (float)D_;
  float qq = 0.f;
  #pragma unroll
  for (int u = 0; u < 8; ++u) { float dd = vv[u] - mean; qq = fmaf(dd, dd, qq); }
  qq = waveAllSum(qq);
  float denom = sqrtf(qq / (float)D_ + 1e-5f);
  #pragma unroll
  for (int u = 0; u < 8; ++u) {
    int d = lane + u * 64;
    out[o1 + d] = (vv[u] - mean) / denom * g[d] + be[d];
  }
}

// ---------------- host ----------------
extern "C" void kernel_launch(void* const* d_in, const int* in_sizes, int n_in,
                              void* d_out, int out_size, void* d_ws, size_t ws_size,
                              hipStream_t stream)
{
  const float* x   = (const float*)d_in[0];
  const float* W[12];
  for (int i = 0; i < 12; ++i) W[i] = (const float*)d_in[1 + i];
  const float* b3  = (const float*)d_in[10];
  const float* b4  = (const float*)d_in[12];
  const float* g1  = (const float*)d_in[13];
  const float* be1 = (const float*)d_in[14];
  const float* g2  = (const float*)d_in[15];
  const float* be2 = (const float*)d_in[16];

  float* outY = (float*)d_out;
  float* outA = outY + (size_t)ROWS_ * D_;

  char* ws = (char*)d_ws;
  size_t off = 0;
  auto alloc = [&](size_t bytes){ size_t cur = off; off += (bytes + 255) & ~(size_t)255; return cur; };

  const size_t oAB  = alloc((size_t)MPAD_ * D_ * 2);   // xln bf16 for MLP
  const size_t oQ   = alloc((size_t)ROWS_ * D_ * 2);   // hbufF region (4 planes, 181MB)
  const size_t oK   = alloc((size_t)ROWS_ * D_ * 2);
  const size_t oV   = alloc((size_t)ROWS_ * D_ * 2);
  const size_t oNX2 = alloc((size_t)ROWS_ * D_ * 2);
  const size_t oR1  = alloc((size_t)ROWS_ * D_ * 4);   // distT -> xln f32
  const size_t oR2  = alloc(62000000);                 // merged/compact -> ypreBF
  const size_t oWT  = alloc(8 * 524288 + 2 * 2097152);
  const size_t oIT  = alloc(44000 * 4);
  const size_t oIC  = alloc(220 * 4);
  const size_t oNWT = alloc(220 * KT_ * 4);
  const size_t oNWC = alloc(B_ * KC_ * 4);
  const size_t oCTT = alloc(220 * KT_ * 4);
  const size_t oCTC = alloc(B_ * KC_ * 4);
  const size_t oX2T = alloc(44000 * 4);
  const size_t oX2C = alloc(220 * 4);
  const size_t oDET = alloc(44000 * 4);
  const size_t oDEC = alloc(220 * 4);
  const size_t oSCT = alloc(44000 * 4);
  const size_t oSCC = alloc(220 * 4);
  const size_t oDMT = alloc(220 * 4);
  const size_t oDMC = alloc(B_ * 4);
  const size_t oPT  = alloc(44000 * 4);
  const size_t oPC  = alloc(220 * 4);
  const size_t oDC  = alloc((size_t)B_ * C_ * C_ * 4);
  (void)ws_size; (void)in_sizes; (void)n_in; (void)out_size;

  hbf*   Abuf   = (hbf*)(ws + oAB);
  hbf*   hbufF  = (hbf*)(ws + oQ);
  float* distT  = (float*)(ws + oR1);
  float* xlnF   = (float*)(ws + oR1);
  float* mergedT = (float*)(ws + oR2);
  float* mergedC = (float*)(ws + oR2 + 40000000);
  hbf*   XCc    = (hbf*)(ws + oR2 + 9100000);
  hbf*   Qc2    = (hbf*)(ws + oR2 + 17400000);
  hbf*   Kc2    = Qc2 + (size_t)MCCP_ * 512;
  hbf*   Vc2    = Kc2 + (size_t)MCCP_ * 512;
  hbf*   Oc2    = (hbf*)(ws + oR2 + 42300000);
  hbf*   nx2c   = (hbf*)(ws + oR2 + 50600000);
  hbf*   XAc    = (hbf*)(ws + oR2 + 9100000);
  hbf*   Qc1    = (hbf*)(ws + oR2 + 14000000);
  hbf*   Kc1    = Qc1 + (size_t)MTCP_ * 512;
  hbf*   Vc1    = Kc1 + (size_t)MTCP_ * 512;
  hbf*   Oc1    = (hbf*)(ws + oR2 + 28700000);
  hbf*   nx1c   = (hbf*)(ws + oR2 + 33600000);
  float* PcG    = (float*)(ws + oR2 + 38500000);
  hbf*   ypreBF = (hbf*)(ws + oR2);
  hbf*   WT[8];
  for (int i = 0; i < 8; ++i) WT[i] = (hbf*)(ws + oWT + (size_t)i * 524288);
  hbf*   W3T = (hbf*)(ws + oWT + 4194304);
  hbf*   W4T = (hbf*)(ws + oWT + 6291456);
  int* idxT = (int*)(ws + oIT);
  int* idxC = (int*)(ws + oIC);
  float* nwT = (float*)(ws + oNWT);
  float* nwC = (float*)(ws + oNWC);
  int* cntT = (int*)(ws + oCTT);
  int* cntC = (int*)(ws + oCTC);
  float* x2T = (float*)(ws + oX2T);
  float* x2C = (float*)(ws + oX2C);
  float* densT = (float*)(ws + oDET);
  float* densC = (float*)(ws + oDEC);
  float* scoreT = (float*)(ws + oSCT);
  float* scoreC = (float*)(ws + oSCC);
  unsigned* dmaxT = (unsigned*)(ws + oDMT);
  unsigned* dmaxC = (unsigned*)(ws + oDMC);
  float* pertT = (float*)(ws + oPT);
  float* pertC = (float*)(ws + oPC);
  float* distC = (float*)(ws + oDC);

  size_t maskOff = (size_t)ROWS_ * D_ + (size_t)B_ * C_ * L_ * L_;
  (void)hipMemsetAsync((char*)d_out + maskOff * sizeof(float), 0,
                 ((size_t)B_ * C_ * L_ * L_ + ROWS_) * sizeof(float), stream);
  (void)hipMemsetAsync(ws + oDMT, 0, 220 * 4, stream);
  (void)hipMemsetAsync(ws + oDMC, 0, B_ * 4, stream);

  for (int i = 0; i < 8; ++i)
    transp_kernel<<<dim3(16, 16), 256, 0, stream>>>(W[i], WT[i], 512, 512);
  transp_kernel<<<dim3(64, 16), 256, 0, stream>>>(W[8],  W3T, 512, 2048);
  transp_kernel<<<dim3(16, 64), 256, 0, stream>>>(W[10], W4T, 2048, 512);

  // P1: RNG + temporal clustering
  pert_kernel<<<173, 256, 0, stream>>>(pertT, pertC);
  x2_kernel<<<11000, 256, 0, stream>>>(x, x2T, 44000, N_, 0);
  dist64_kernel<<<dim3(10, 220), 256, 0, stream>>>(x, x2T, distT, dmaxT, N_, 4, 0);
  knn_density_kernel<<<11000, 256, 0, stream>>>(distT, pertT, densT, 44000, N_, 20, 0);
  dparent_score_kernel<<<11000, 256, 0, stream>>>(distT, densT, dmaxT, scoreT, 44000, N_);
  seeds_assign_kernel<<<220, 256, 0, stream>>>(scoreT, distT, idxT, nwT, cntT, N_, KT_);
  merge_t_kernel<<<dim3(4, 220), 128, 0, stream>>>(x, idxT, nwT, mergedT);

  // P2: channel clustering
  x2_kernel<<<55, 256, 0, stream>>>(x, x2C, 220, C_, 1);
  dist64_kernel<<<dim3(1, 4), 256, 0, stream>>>(x, x2C, distC, dmaxC, C_, 1, 1);
  knn_density_kernel<<<55, 256, 0, stream>>>(distC, pertC, densC, 220, C_, 5, 1);
  dparent_score_kernel<<<55, 256, 0, stream>>>(distC, densC, dmaxC, scoreC, 220, C_);
  seeds_assign_kernel<<<4, 256, 0, stream>>>(scoreC, distC, idxC, nwC, cntC, C_, KC_);
  merge_c_kernel<<<dim3(804, 4), 128, 0, stream>>>(x, idxC, nwC, mergedC);

  // P3: channel attention (compact, 8040 rows)
  cast_xcc_bf<<<2016, 256, 0, stream>>>(mergedC, XCc);
  gemm_mfma<hbf, 4><<<dim3(12, 63), 256, 0, stream>>>(XCc, WT[4], Qc2, nullptr, MCC_, 1536, 512, (size_t)MCCP_ * 512);
  attn_compact_c<<<804, 256, 0, stream>>>(Qc2, Kc2, Vc2, cntC, Oc2);
  gemm_mfma<hbf, 0><<<dim3(4, 63), 256, 0, stream>>>(Oc2, WT[7], nx2c, nullptr, MCC_, 512, 512, 0);

  // P4: temporal attention (compact, 4620 rows)
  build_xac_bf<<<1184, 256, 0, stream>>>(x, mergedT, XAc);
  gemm_mfma<hbf, 4><<<dim3(12, 37), 256, 0, stream>>>(XAc, WT[0], Qc1, nullptr, MTC_, 1536, 512, (size_t)MTCP_ * 512);
  attn_compact_t<<<220, 256, 0, stream>>>(Qc1, Kc1, Vc1, cntT, PcG, Oc1);
  expand_attn<<<11055, 256, 0, stream>>>(PcG, idxT, outA);
  gemm_mfma<hbf, 0><<<dim3(4, 37), 256, 0, stream>>>(Oc1, WT[3], nx1c, nullptr, MTC_, 512, 512, 0);

  // P5: combine + LN1 (writes xln f32 + bf16 copy)
  combine_ln1_kernel<<<ROWS_, 64, 0, stream>>>(x, nx1c, nx2c, idxT, idxC, g1, be1, xlnF, Abuf);

  // P6: MLP unchunked (narrow 128x128 GEMMs) + LN2
  gemm_mfma<hbf, 2><<<dim3(16, 346), 256, 0, stream>>>(Abuf, W3T, hbufF, b3, ROWS_, 2048, 512, 0);
  gemm_mfma<hbf, 1><<<dim3(4, 346), 256, 0, stream>>>(hbufF, W4T, ypreBF, b4, ROWS_, 512, 2048, 0);
  ln2_kernel<<<ROWS_, 64, 0, stream>>>(xlnF, ypreBF, g2, be2, outY);
}